// Round 4
// baseline (129.773 us; speedup 1.0000x reference)
//
#include <hip/hip_runtime.h>

#define K_CW 256
#define PPT 4  // points per thread

struct P8 { float4 a; float4 b; };  // {c0,c1,c2,c3} {csq,pad,pad,pad} -> one s_load_dwordx8

// Build packed codebook table in ws. csq uses numpy rounding:
// ((c0*c0 + c1*c1) + c2*c2) + c3*c3  (sequential adds of rounded squares)
__global__ void vq_pack_kernel(const float* __restrict__ tlut, float* __restrict__ pk) {
    int k = threadIdx.x;  // 256 threads, 1 block
    float c0 = tlut[k * 4 + 0];
    float c1 = tlut[k * 4 + 1];
    float c2 = tlut[k * 4 + 2];
    float c3 = tlut[k * 4 + 3];
    float s = __fadd_rn(__fadd_rn(__fadd_rn(__fmul_rn(c0, c0), __fmul_rn(c1, c1)),
                                  __fmul_rn(c2, c2)),
                        __fmul_rn(c3, c3));
    pk[k * 8 + 0] = c0; pk[k * 8 + 1] = c1; pk[k * 8 + 2] = c2; pk[k * 8 + 3] = c3;
    pk[k * 8 + 4] = s;  pk[k * 8 + 5] = 0.f; pk[k * 8 + 6] = 0.f; pk[k * 8 + 7] = 0.f;
}

__global__ __launch_bounds__(256) void vq_argmin_kernel(
    const float* __restrict__ X,
    const float* __restrict__ tlut,
    const float* __restrict__ pk,
    float* __restrict__ outX,   // [B,4] reconstruction
    float* __restrict__ outS,   // [B] state, stored as float
    int B) {
    const int tid = blockIdx.x * blockDim.x + threadIdx.x;
    const int stride = B / PPT;       // strided point assignment -> coalesced per instr
    if (tid >= stride) return;

    const float4* __restrict__ X4 = reinterpret_cast<const float4*>(X);
    const float4* __restrict__ T4 = reinterpret_cast<const float4*>(tlut);
    const P8* __restrict__ PK = reinterpret_cast<const P8*>(pk);

    float x0[PPT], x1[PPT], x2[PPT], x3[PPT], xsq[PPT], bestd[PPT];
    int besti[PPT];

    #pragma unroll
    for (int i = 0; i < PPT; ++i) {
        const float4 xv = X4[tid + i * stride];
        x0[i] = xv.x; x1[i] = xv.y; x2[i] = xv.z; x3[i] = xv.w;
        // x_sq with numpy rounding: sequential adds of rounded squares
        xsq[i] = __fadd_rn(__fadd_rn(__fadd_rn(__fmul_rn(xv.x, xv.x), __fmul_rn(xv.y, xv.y)),
                                     __fmul_rn(xv.z, xv.z)),
                           __fmul_rn(xv.w, xv.w));
        bestd[i] = __builtin_inff();
        besti[i] = 0;
    }

    // software-pipelined wave-uniform codebook stream (s_load_dwordx8 per k)
    P8 cur = PK[0];
    #pragma unroll 4
    for (int k = 0; k < K_CW; ++k) {
        P8 nxt;
        if (k + 1 < K_CW) nxt = PK[k + 1];   // prefetch next entry (scalar pipe)
        const float4 c = cur.a;
        const float cs = cur.b.x;
        #pragma unroll
        for (int i = 0; i < PPT; ++i) {
            // cross: numpy einsum `accum += a*b` with fp-contract -> ascending FMA chain
            float cross = __fmul_rn(x0[i], c.x);
            cross = __fmaf_rn(x1[i], c.y, cross);
            cross = __fmaf_rn(x2[i], c.z, cross);
            cross = __fmaf_rn(x3[i], c.w, cross);
            // (x_sq - 2*cross) + c_sq ; fma(-2,cross,xsq) == rn(xsq - rn(2*cross)) exactly
            float t = __fmaf_rn(-2.0f, cross, xsq[i]);
            float d = __fadd_rn(t, cs);
            // argmin, first occurrence (strict <), ascending k.
            // besti via cmp+cndmask; bestd via v_min_f32 (no vcc dependency).
            besti[i] = (d < bestd[i]) ? k : besti[i];
            bestd[i] = fminf(d, bestd[i]);
        }
        cur = nxt;
    }

    #pragma unroll
    for (int i = 0; i < PPT; ++i) {
        const int p = tid + i * stride;
        reinterpret_cast<float4*>(outX)[p] = T4[besti[i]];
        outS[p] = (float)besti[i];
    }
}

extern "C" void kernel_launch(void* const* d_in, const int* in_sizes, int n_in,
                              void* d_out, int out_size, void* d_ws, size_t ws_size,
                              hipStream_t stream) {
    const float* X    = (const float*)d_in[0];   // [B,4]
    const float* tlut = (const float*)d_in[1];   // [256,4]
    const int B = in_sizes[0] / 4;

    float* outX = (float*)d_out;          // first B*4 floats: hatX
    float* outS = outX + (size_t)B * 4;   // next B floats: state (as float)

    float* pk = (float*)d_ws;             // 256*8 floats packed codebook

    vq_pack_kernel<<<1, 256, 0, stream>>>(tlut, pk);

    const int threads = B / PPT;          // 262144 for B=1M
    const int block = 256;
    const int grid = (threads + block - 1) / block;
    vq_argmin_kernel<<<grid, block, 0, stream>>>(X, tlut, pk, outX, outS, B);
}

// Round 5
// 123.225 us; speedup vs baseline: 1.0531x; 1.0531x over previous
//
#include <hip/hip_runtime.h>

#define K_CW 256
#define PPT 4  // points per thread

// Build packed codebook table in ws: per k, {c0,c1,c2,c3, csq,0,0,0} (32 B).
// csq uses numpy rounding: ((c0*c0 + c1*c1) + c2*c2) + c3*c3
__global__ void vq_pack_kernel(const float* __restrict__ tlut, float* __restrict__ pk) {
    int k = threadIdx.x;  // 256 threads, 1 block
    float c0 = tlut[k * 4 + 0];
    float c1 = tlut[k * 4 + 1];
    float c2 = tlut[k * 4 + 2];
    float c3 = tlut[k * 4 + 3];
    float s = __fadd_rn(__fadd_rn(__fadd_rn(__fmul_rn(c0, c0), __fmul_rn(c1, c1)),
                                  __fmul_rn(c2, c2)),
                        __fmul_rn(c3, c3));
    pk[k * 8 + 0] = c0; pk[k * 8 + 1] = c1; pk[k * 8 + 2] = c2; pk[k * 8 + 3] = c3;
    pk[k * 8 + 4] = s;  pk[k * 8 + 5] = 0.f; pk[k * 8 + 6] = 0.f; pk[k * 8 + 7] = 0.f;
}

__global__ __launch_bounds__(256) void vq_argmin_kernel(
    const float* __restrict__ X,
    const float* __restrict__ tlut,
    const float* __restrict__ pk,
    float* __restrict__ outX,   // [B,4] reconstruction
    float* __restrict__ outS,   // [B] state, stored as float
    int B) {
    // Packed codebook in LDS: entry k at cb[2k] = {c0..c3}, cb[2k+1].x = csq.
    // All lanes read the same address -> broadcast, conflict-free; with
    // unroll the reads become ds_read_b128 with immediate offsets (no VALU).
    __shared__ float4 cb[2 * K_CW];  // 8 KB

    const int t = threadIdx.x;
    {
        const float4* __restrict__ PKv = reinterpret_cast<const float4*>(pk);
        cb[t] = PKv[t];
        cb[t + 256] = PKv[t + 256];
    }
    __syncthreads();

    const int tid = blockIdx.x * blockDim.x + t;
    const int stride = B / PPT;       // strided point assignment -> coalesced
    if (tid >= stride) return;

    const float4* __restrict__ X4 = reinterpret_cast<const float4*>(X);
    const float4* __restrict__ T4 = reinterpret_cast<const float4*>(tlut);

    float x0[PPT], x1[PPT], x2[PPT], x3[PPT], xsq[PPT], bestd[PPT];
    int besti[PPT];

    #pragma unroll
    for (int i = 0; i < PPT; ++i) {
        const float4 xv = X4[tid + i * stride];
        x0[i] = xv.x; x1[i] = xv.y; x2[i] = xv.z; x3[i] = xv.w;
        // x_sq with numpy rounding: sequential adds of rounded squares
        xsq[i] = __fadd_rn(__fadd_rn(__fadd_rn(__fmul_rn(xv.x, xv.x), __fmul_rn(xv.y, xv.y)),
                                     __fmul_rn(xv.z, xv.z)),
                           __fmul_rn(xv.w, xv.w));
        bestd[i] = __builtin_inff();
        besti[i] = 0;
    }

    #pragma unroll 8
    for (int k = 0; k < K_CW; ++k) {
        const float4 c = cb[2 * k];       // uniform addr -> broadcast ds_read_b128
        const float cs = cb[2 * k + 1].x; // ds_read_b32, imm offset
        #pragma unroll
        for (int i = 0; i < PPT; ++i) {
            // cross: numpy einsum `accum += a*b` with fp-contract -> ascending FMA chain
            float cross = __fmul_rn(x0[i], c.x);
            cross = __fmaf_rn(x1[i], c.y, cross);
            cross = __fmaf_rn(x2[i], c.z, cross);
            cross = __fmaf_rn(x3[i], c.w, cross);
            // (x_sq - 2*cross) + c_sq ; fma(-2,cross,xsq) == rn(xsq - rn(2*cross)) exactly
            float t2 = __fmaf_rn(-2.0f, cross, xsq[i]);
            float d = __fadd_rn(t2, cs);
            // argmin, first occurrence (strict <), ascending k:
            // index via cmp+cndmask, value via v_min (independent ops)
            besti[i] = (d < bestd[i]) ? k : besti[i];
            bestd[i] = fminf(d, bestd[i]);
        }
    }

    #pragma unroll
    for (int i = 0; i < PPT; ++i) {
        const int p = tid + i * stride;
        reinterpret_cast<float4*>(outX)[p] = T4[besti[i]];
        outS[p] = (float)besti[i];
    }
}

extern "C" void kernel_launch(void* const* d_in, const int* in_sizes, int n_in,
                              void* d_out, int out_size, void* d_ws, size_t ws_size,
                              hipStream_t stream) {
    const float* X    = (const float*)d_in[0];   // [B,4]
    const float* tlut = (const float*)d_in[1];   // [256,4]
    const int B = in_sizes[0] / 4;

    float* outX = (float*)d_out;          // first B*4 floats: hatX
    float* outS = outX + (size_t)B * 4;   // next B floats: state (as float)

    float* pk = (float*)d_ws;             // 256*8 floats packed codebook

    vq_pack_kernel<<<1, 256, 0, stream>>>(tlut, pk);

    const int threads = B / PPT;          // 262144 for B=1M
    const int block = 256;
    const int grid = (threads + block - 1) / block;
    vq_argmin_kernel<<<grid, block, 0, stream>>>(X, tlut, pk, outX, outS, B);
}

// Round 6
// 116.234 us; speedup vs baseline: 1.1165x; 1.0601x over previous
//
#include <hip/hip_runtime.h>

#define K_CW 256
#define PPT 4      // points per thread
#define KHALF 128  // k-range per thread (split-K by 2)

// Precompute c_sq[k] with numpy rounding: ((c0*c0 + c1*c1) + c2*c2) + c3*c3
__global__ void vq_csq_kernel(const float* __restrict__ tlut, float* __restrict__ csq) {
    int k = threadIdx.x;  // 256 threads, 1 block
    float c0 = tlut[k * 4 + 0];
    float c1 = tlut[k * 4 + 1];
    float c2 = tlut[k * 4 + 2];
    float c3 = tlut[k * 4 + 3];
    float s = __fadd_rn(__fadd_rn(__fadd_rn(__fmul_rn(c0, c0), __fmul_rn(c1, c1)),
                                  __fmul_rn(c2, c2)),
                        __fmul_rn(c3, c3));
    csq[k] = s;
}

__global__ __launch_bounds__(512) void vq_argmin_kernel(
    const float* __restrict__ X,
    const float* __restrict__ tlut,
    const float* __restrict__ csq,
    float* __restrict__ outX,   // [B,4] reconstruction
    float* __restrict__ outS,   // [B] state, stored as float
    int B) {
    // split-K: lower 256 threads scan k in [0,128), upper 256 scan [128,256),
    // both on the SAME 4 points; merge via LDS. 512-thr blocks restore full
    // 32 waves/CU while keeping PPT=4 instruction amortization.
    __shared__ float4 sd[256];  // upper half's bestd
    __shared__ int4   si[256];  // upper half's besti

    const int t = threadIdx.x;
    const int tt = t & 255;
    const int half = t >> 8;
    // wave-uniform by construction (waves 0-3 -> 0, waves 4-7 -> 128);
    // readfirstlane tells the compiler so codebook reads stay s_load.
    const int kbase = __builtin_amdgcn_readfirstlane(half << 7);

    const int g = blockIdx.x * 256 + tt;   // point-group id
    const int stride = B / PPT;            // 262144: strided points -> coalesced

    const float4* __restrict__ X4 = reinterpret_cast<const float4*>(X);
    const float4* __restrict__ T4 = reinterpret_cast<const float4*>(tlut);

    float x0[PPT], x1[PPT], x2[PPT], x3[PPT], xsq[PPT], bestd[PPT];
    int besti[PPT];

    #pragma unroll
    for (int i = 0; i < PPT; ++i) {
        const float4 xv = X4[g + i * stride];
        x0[i] = xv.x; x1[i] = xv.y; x2[i] = xv.z; x3[i] = xv.w;
        // x_sq with numpy rounding: sequential adds of rounded squares
        xsq[i] = __fadd_rn(__fadd_rn(__fadd_rn(__fmul_rn(xv.x, xv.x), __fmul_rn(xv.y, xv.y)),
                                     __fmul_rn(xv.z, xv.z)),
                           __fmul_rn(xv.w, xv.w));
        bestd[i] = __builtin_inff();
        besti[i] = kbase;
    }

    #pragma unroll 8
    for (int kk = 0; kk < KHALF; ++kk) {
        const int k = kbase + kk;          // wave-uniform -> s_load path
        const float4 c = T4[k];
        const float cs = csq[k];
        #pragma unroll
        for (int i = 0; i < PPT; ++i) {
            // cross: numpy einsum `accum += a*b` with fp-contract -> ascending FMA chain
            float cross = __fmul_rn(x0[i], c.x);
            cross = __fmaf_rn(x1[i], c.y, cross);
            cross = __fmaf_rn(x2[i], c.z, cross);
            cross = __fmaf_rn(x3[i], c.w, cross);
            // (x_sq - 2*cross) + c_sq ; fma(-2,cross,xsq) == rn(xsq - rn(2*cross)) exactly
            float t2 = __fmaf_rn(-2.0f, cross, xsq[i]);
            float d = __fadd_rn(t2, cs);
            // argmin, first occurrence (strict <), ascending k:
            // index via cmp+cndmask, value via v_min (independent ops)
            besti[i] = (d < bestd[i]) ? k : besti[i];
            bestd[i] = fminf(d, bestd[i]);
        }
    }

    if (half == 1) {
        sd[tt] = make_float4(bestd[0], bestd[1], bestd[2], bestd[3]);
        si[tt] = make_int4(besti[0], besti[1], besti[2], besti[3]);
    }
    __syncthreads();
    if (half == 0) {
        const float4 od = sd[tt];
        const int4   oi = si[tt];
        // upper half covers larger k: it wins only on strictly smaller distance
        // (tie -> lower half = smaller k = np.argmin first occurrence)
        if (od.x < bestd[0]) { bestd[0] = od.x; besti[0] = oi.x; }
        if (od.y < bestd[1]) { bestd[1] = od.y; besti[1] = oi.y; }
        if (od.z < bestd[2]) { bestd[2] = od.z; besti[2] = oi.z; }
        if (od.w < bestd[3]) { bestd[3] = od.w; besti[3] = oi.w; }

        #pragma unroll
        for (int i = 0; i < PPT; ++i) {
            const int p = g + i * stride;
            reinterpret_cast<float4*>(outX)[p] = T4[besti[i]];
            outS[p] = (float)besti[i];
        }
    }
}

extern "C" void kernel_launch(void* const* d_in, const int* in_sizes, int n_in,
                              void* d_out, int out_size, void* d_ws, size_t ws_size,
                              hipStream_t stream) {
    const float* X    = (const float*)d_in[0];   // [B,4]
    const float* tlut = (const float*)d_in[1];   // [256,4]
    const int B = in_sizes[0] / 4;

    float* outX = (float*)d_out;          // first B*4 floats: hatX
    float* outS = outX + (size_t)B * 4;   // next B floats: state (as float)

    float* csq = (float*)d_ws;            // 256 floats of scratch

    vq_csq_kernel<<<1, 256, 0, stream>>>(tlut, csq);

    const int groups = B / PPT;           // 262144 point-groups
    const int grid = groups / 256;        // 1024 blocks of 512 threads
    vq_argmin_kernel<<<grid, 512, 0, stream>>>(X, tlut, csq, outX, outS, B);
}

// Round 7
// 115.486 us; speedup vs baseline: 1.1237x; 1.0065x over previous
//
#include <hip/hip_runtime.h>

#define K_CW 256
#define PPT 4       // points per thread
#define NQ 4        // split-K quarters
#define KQ (K_CW / NQ)  // 64 k per quarter

struct P8 { float4 a; float4 b; };  // {c0,c1,c2,c3} {csq,pad,pad,pad} -> one s_load_dwordx8

// Build packed codebook in ws. csq uses numpy rounding:
// ((c0*c0 + c1*c1) + c2*c2) + c3*c3  (sequential adds of rounded squares)
__global__ void vq_pack_kernel(const float* __restrict__ tlut, float* __restrict__ pk) {
    int k = threadIdx.x;  // 256 threads, 1 block
    float c0 = tlut[k * 4 + 0];
    float c1 = tlut[k * 4 + 1];
    float c2 = tlut[k * 4 + 2];
    float c3 = tlut[k * 4 + 3];
    float s = __fadd_rn(__fadd_rn(__fadd_rn(__fmul_rn(c0, c0), __fmul_rn(c1, c1)),
                                  __fmul_rn(c2, c2)),
                        __fmul_rn(c3, c3));
    pk[k * 8 + 0] = c0; pk[k * 8 + 1] = c1; pk[k * 8 + 2] = c2; pk[k * 8 + 3] = c3;
    pk[k * 8 + 4] = s;  pk[k * 8 + 5] = 0.f; pk[k * 8 + 6] = 0.f; pk[k * 8 + 7] = 0.f;
}

__global__ __launch_bounds__(1024, 8) void vq_argmin_kernel(
    const float* __restrict__ X,
    const float* __restrict__ tlut,
    const float* __restrict__ pk,
    float* __restrict__ outX,   // [B,4] reconstruction
    float* __restrict__ outS,   // [B] state, stored as float
    int B) {
    // split-K x4: quarter q scans k in [64q, 64q+64) on the same 4 points.
    // 1024-thr blocks -> 16 waves; 1024 blocks -> 2 resident + 2 queued per CU.
    __shared__ float4 sd[3 * 256];  // quarters 1..3 bestd
    __shared__ int4   si[3 * 256];  // quarters 1..3 besti

    const int t = threadIdx.x;
    const int tt = t & 255;
    const int q = t >> 8;  // wave-uniform (wave = 64 consecutive threads)
    const int kbase = __builtin_amdgcn_readfirstlane(q << 6);

    const int g = blockIdx.x * 256 + tt;   // point-group id
    const int stride = B / PPT;            // strided points -> coalesced

    const float4* __restrict__ X4 = reinterpret_cast<const float4*>(X);
    const float4* __restrict__ T4 = reinterpret_cast<const float4*>(tlut);
    const P8* __restrict__ PK = reinterpret_cast<const P8*>(pk);

    float x0[PPT], x1[PPT], x2[PPT], x3[PPT], xsq[PPT], bestd[PPT];
    int besti[PPT];

    #pragma unroll
    for (int i = 0; i < PPT; ++i) {
        const float4 xv = X4[g + i * stride];
        x0[i] = xv.x; x1[i] = xv.y; x2[i] = xv.z; x3[i] = xv.w;
        // x_sq with numpy rounding: sequential adds of rounded squares
        xsq[i] = __fadd_rn(__fadd_rn(__fadd_rn(__fmul_rn(xv.x, xv.x), __fmul_rn(xv.y, xv.y)),
                                     __fmul_rn(xv.z, xv.z)),
                           __fmul_rn(xv.w, xv.w));
        bestd[i] = __builtin_inff();
        besti[i] = kbase;
    }

    #pragma unroll 16
    for (int kk = 0; kk < KQ; ++kk) {
        const int k = kbase + kk;          // wave-uniform -> scalar path
        const P8 e = PK[k];                // one s_load_dwordx8 per k
        const float4 c = e.a;
        const float cs = e.b.x;
        #pragma unroll
        for (int i = 0; i < PPT; ++i) {
            // cross: numpy einsum `accum += a*b` with fp-contract -> ascending FMA chain
            float cross = __fmul_rn(x0[i], c.x);
            cross = __fmaf_rn(x1[i], c.y, cross);
            cross = __fmaf_rn(x2[i], c.z, cross);
            cross = __fmaf_rn(x3[i], c.w, cross);
            // (x_sq - 2*cross) + c_sq ; fma(-2,cross,xsq) == rn(xsq - rn(2*cross)) exactly
            float t2 = __fmaf_rn(-2.0f, cross, xsq[i]);
            float d = __fadd_rn(t2, cs);
            // argmin, first occurrence (strict <), ascending k:
            // index via cmp+cndmask, value via v_min (independent ops)
            besti[i] = (d < bestd[i]) ? k : besti[i];
            bestd[i] = fminf(d, bestd[i]);
        }
    }

    if (q > 0) {
        sd[(q - 1) * 256 + tt] = make_float4(bestd[0], bestd[1], bestd[2], bestd[3]);
        si[(q - 1) * 256 + tt] = make_int4(besti[0], besti[1], besti[2], besti[3]);
    }
    __syncthreads();
    if (q == 0) {
        // merge quarters in ascending k order; strict '<' so the earlier
        // quarter (smaller k) wins ties -> np.argmin first-occurrence
        #pragma unroll
        for (int j = 0; j < 3; ++j) {
            const float4 od = sd[j * 256 + tt];
            const int4   oi = si[j * 256 + tt];
            if (od.x < bestd[0]) { bestd[0] = od.x; besti[0] = oi.x; }
            if (od.y < bestd[1]) { bestd[1] = od.y; besti[1] = oi.y; }
            if (od.z < bestd[2]) { bestd[2] = od.z; besti[2] = oi.z; }
            if (od.w < bestd[3]) { bestd[3] = od.w; besti[3] = oi.w; }
        }
        #pragma unroll
        for (int i = 0; i < PPT; ++i) {
            const int p = g + i * stride;
            reinterpret_cast<float4*>(outX)[p] = T4[besti[i]];
            outS[p] = (float)besti[i];
        }
    }
}

extern "C" void kernel_launch(void* const* d_in, const int* in_sizes, int n_in,
                              void* d_out, int out_size, void* d_ws, size_t ws_size,
                              hipStream_t stream) {
    const float* X    = (const float*)d_in[0];   // [B,4]
    const float* tlut = (const float*)d_in[1];   // [256,4]
    const int B = in_sizes[0] / 4;

    float* outX = (float*)d_out;          // first B*4 floats: hatX
    float* outS = outX + (size_t)B * 4;   // next B floats: state (as float)

    float* pk = (float*)d_ws;             // 256*8 floats packed codebook

    vq_pack_kernel<<<1, 256, 0, stream>>>(tlut, pk);

    const int groups = B / PPT;           // 262144 point-groups
    const int grid = groups / 256;        // 1024 blocks of 1024 threads
    vq_argmin_kernel<<<grid, 1024, 0, stream>>>(X, tlut, pk, outX, outS, B);
}